// Round 2
// baseline (299.559 us; speedup 1.0000x reference)
//
#include <hip/hip_runtime.h>
#include <stdint.h>

// MultiHeadedAttention: B=2,S=2048,D=1024,H=16,DK=64
// Pipeline: f32->f16 cvt; QKV proj GEMMs (MFMA f16); flash attention with
// rel_pos_bias + bool mask; output proj GEMM -> f32.

typedef _Float16 f16;
typedef _Float16 f16x8 __attribute__((ext_vector_type(8)));
typedef _Float16 f16x4 __attribute__((ext_vector_type(4)));
typedef float f32x4 __attribute__((ext_vector_type(4)));

#define LOG2E 1.44269504088896340736f

__device__ __forceinline__ void gload16(const void* g, void* l) {
  __builtin_amdgcn_global_load_lds(
      (const __attribute__((address_space(1))) unsigned int*)g,
      (__attribute__((address_space(3))) unsigned int*)l, 16, 0, 0);
}

// ---------------- f32 -> f16 conversion (4 elems/thread, exact grid) ------
__global__ __launch_bounds__(256) void cvt_f32_f16(const float* __restrict__ in,
                                                   f16* __restrict__ out, int n4) {
  const int i = blockIdx.x * 256 + threadIdx.x;
  if (i >= n4) return;
  const float4 v = ((const float4*)in)[i];
  f16x4 o = {(f16)v.x, (f16)v.y, (f16)v.z, (f16)v.w};
  ((f16x4*)out)[i] = o;
}

// ---------------- mask dtype classify + canonicalize to u8 ----------------
__global__ void mask_detect(const uint8_t* __restrict__ m, int* __restrict__ flag) {
  __shared__ int s_off, s_weird;
  const int t = threadIdx.x;
  if (t == 0) { s_off = 0; s_weird = 0; }
  __syncthreads();
  int f_off = 0, f_weird = 0;
  for (int i = t; i < 8192; i += 256) {
    const uint8_t v = m[i];
    if ((i & 3) && v) f_off = 1;
    if (v > 1) f_weird = 1;
  }
  if (f_off) atomicOr(&s_off, 1);
  if (f_weird) atomicOr(&s_weird, 1);
  __syncthreads();
  if (t == 0) *flag = (s_off && !s_weird) ? 1 : 0;  // 1 => byte-sized bool
}

__global__ __launch_bounds__(256) void mask_canon(const uint8_t* __restrict__ m,
                                                  uint8_t* __restrict__ out,
                                                  const int* __restrict__ flag) {
  const int i = (blockIdx.x * 256 + threadIdx.x) * 4;  // grid covers 8388608
  uchar4 o;
  if (*flag) {
    const uchar4 v = *(const uchar4*)(m + i);
    o = make_uchar4(v.x != 0, v.y != 0, v.z != 0, v.w != 0);
  } else {
    const int4 v = *(const int4*)((const int*)m + i);
    o = make_uchar4(v.x != 0, v.y != 0, v.z != 0, v.w != 0);
  }
  *(uchar4*)(out + i) = o;
}

// ---------------- GEMM: C[m,n] = sum_k A[m,k]*B[n,k] + bias[n] ------------
// MODE 0: f16 out [B,H,S,DK]; MODE 1: f16 out [B,H,DK,S]; MODE 2: f32 [M,N]
template <int MODE>
__global__ __launch_bounds__(256, 2) void gemm_bt(const f16* __restrict__ A,
                                                  const f16* __restrict__ Bw,
                                                  const float* __restrict__ bias,
                                                  void* __restrict__ outp) {
  constexpr int K = 1024;
  const int t = threadIdx.x;
  const int w = t >> 6, lane = t & 63, l15 = lane & 15, l4 = lane >> 4;
  const int bm = (int)(blockIdx.x >> 4) * 128;
  const int bn = (int)(blockIdx.x & 15) * 64;

  __shared__ f16 As[2][128 * 32];
  __shared__ f16 Bs[2][64 * 32];

  const f16* a0 = A + (size_t)(bm + (t >> 2)) * K + (t & 3) * 8;
  const f16* a1 = a0 + (size_t)64 * K;
  const f16* b0 = Bw + (size_t)(bn + (t >> 2)) * K + (t & 3) * 8;

  f32x4 acc[2][4];
#pragma unroll
  for (int m = 0; m < 2; ++m)
#pragma unroll
    for (int n = 0; n < 4; ++n) acc[m][n] = (f32x4){0.f, 0.f, 0.f, 0.f};

#define STAGE_G(buf, k0)                          \
  do {                                            \
    gload16(a0 + (k0), &As[buf][w * 512]);        \
    gload16(a1 + (k0), &As[buf][2048 + w * 512]); \
    gload16(b0 + (k0), &Bs[buf][w * 512]);        \
  } while (0)

  STAGE_G(0, 0);
  __syncthreads();
  int cur = 0;
#pragma unroll 1
  for (int kt = 0; kt < 32; ++kt) {
    if (kt < 31) STAGE_G(cur ^ 1, (kt + 1) * 32);
    const f16* ap = &As[cur][(w * 32 + l15) * 32 + l4 * 8];
    const f16* bp = &Bs[cur][l15 * 32 + l4 * 8];
    f16x8 af[2], bfr[4];
#pragma unroll
    for (int m = 0; m < 2; ++m) af[m] = *(const f16x8*)(ap + m * 512);
#pragma unroll
    for (int n = 0; n < 4; ++n) bfr[n] = *(const f16x8*)(bp + n * 512);
#pragma unroll
    for (int m = 0; m < 2; ++m)
#pragma unroll
      for (int n = 0; n < 4; ++n)
        acc[m][n] = __builtin_amdgcn_mfma_f32_16x16x32_f16(af[m], bfr[n], acc[m][n], 0, 0, 0);
    __syncthreads();
    cur ^= 1;
  }
#undef STAGE_G

#pragma unroll
  for (int m = 0; m < 2; ++m) {
    const int r0 = bm + w * 32 + m * 16 + (l4 << 2);
#pragma unroll
    for (int n = 0; n < 4; ++n) {
      const int c = bn + n * 16 + l15;
      const float bv = bias[c];
#pragma unroll
      for (int j = 0; j < 4; ++j) {
        const int r = r0 + j;
        const float v = acc[m][n][j] + bv;
        if (MODE == 0) {
          const int b_ = r >> 11, s = r & 2047, h_ = c >> 6, dk = c & 63;
          ((f16*)outp)[(((size_t)b_ * 16 + h_) * 2048 + s) * 64 + dk] = (f16)v;
        } else if (MODE == 1) {
          const int b_ = r >> 11, s = r & 2047, h_ = c >> 6, dk = c & 63;
          ((f16*)outp)[(((size_t)b_ * 16 + h_) * 64 + dk) * 2048 + s] = (f16)v;
        } else {
          ((float*)outp)[(size_t)r * 1024 + c] = v;
        }
      }
    }
  }
}

// ---------------- flash attention -----------------------------------------
// 1024 blocks: bid -> (qt 0..31, b, h), h outermost. 4 waves x 16 q-rows,
// kv tiles of 64. launch_bounds(256,4): 4 blocks/CU (LDS 24KB, VGPR<=128).
// bias+mask prefetched to regs inside the staging window so one barrier
// drain covers K/V gload_lds AND the bias/mask latency.
__device__ __forceinline__ const f16x8* swzr(const f16* base, int row, int bytecol) {
  return (const f16x8*)((const char*)base + row * 128 + (bytecol ^ ((row & 7) << 4)));
}

__global__ __launch_bounds__(256, 4) void attn_fwd(
    const f16* __restrict__ Qp, const f16* __restrict__ Kp,
    const f16* __restrict__ Vt, const float* __restrict__ bias,
    const uint8_t* __restrict__ mask, f16* __restrict__ X) {
  constexpr int S = 2048;
  const int bid = blockIdx.x;
  const int qt = bid & 31, b = (bid >> 5) & 1, h = bid >> 6;
  const int t = threadIdx.x, w = t >> 6, lane = t & 63;
  const int l15 = lane & 15, l4 = lane >> 4;
  const int q0 = qt * 64 + w * 16;

  const f16* Qbh = Qp + (size_t)(b * 16 + h) * S * 64;
  const f16* Kbh = Kp + (size_t)(b * 16 + h) * S * 64;
  const f16* Vbh = Vt + (size_t)(b * 16 + h) * 64 * S;
  const float* biash = bias + (size_t)h * S * S;
  const uint8_t* maskb = mask + (size_t)b * S * S;

  __shared__ f16 Ks[64 * 64];     // [kv][dk], swizzled
  __shared__ f16 Vs[64 * 64];     // [dk][kv], swizzled
  __shared__ f16 Ps[4][16 * 64];  // per-wave P, swizzled

  // row offsets (elements) shared by bias and mask: qrow*S + l15
  int ro[4];
#pragma unroll
  for (int j = 0; j < 4; ++j) ro[j] = (q0 + l4 * 4 + j) * S + l15;

  // Q fragments: row = l15, k = l4*8 + i within 32-k window
  f16x8 qf[2];
#pragma unroll
  for (int ks = 0; ks < 2; ++ks)
    qf[ks] = *(const f16x8*)(Qbh + (size_t)(q0 + l15) * 64 + ks * 32 + l4 * 8);

  f32x4 oacc[4];
#pragma unroll
  for (int n = 0; n < 4; ++n) oacc[n] = (f32x4){0.f, 0.f, 0.f, 0.f};
  float mrow[4], lrow[4];
#pragma unroll
  for (int j = 0; j < 4; ++j) { mrow[j] = -3e38f; lrow[j] = 0.f; }

  const int srow = t >> 3;
  const int scol = (((t & 7) ^ (srow & 7)) << 3);

#pragma unroll 1
  for (int kt = 0; kt < 32; ++kt) {
    const int k0 = kt * 64;
    __syncthreads();  // all waves done reading previous K/V tile
    gload16(Kbh + (size_t)(k0 + srow) * 64 + scol, &Ks[w * 512]);
    gload16(Kbh + (size_t)(k0 + 32 + srow) * 64 + scol, &Ks[2048 + w * 512]);
    gload16(Vbh + (size_t)srow * S + k0 + scol, &Vs[w * 512]);
    gload16(Vbh + (size_t)(32 + srow) * S + k0 + scol, &Vs[2048 + w * 512]);
    // bias+mask register prefetch — in flight alongside the LDS staging
    float breg[4][4];
    int mreg[4][4];
#pragma unroll
    for (int j = 0; j < 4; ++j)
#pragma unroll
      for (int n = 0; n < 4; ++n) {
        breg[j][n] = biash[ro[j] + k0 + n * 16];
        mreg[j][n] = maskb[ro[j] + k0 + n * 16];
      }
    __syncthreads();  // vmcnt(0): LDS tiles + bias/mask regs all ready

    // ---- scores = Q.K^T ----
    f32x4 sacc[4];
#pragma unroll
    for (int n = 0; n < 4; ++n) sacc[n] = (f32x4){0.f, 0.f, 0.f, 0.f};
#pragma unroll
    for (int n = 0; n < 4; ++n)
#pragma unroll
      for (int ks = 0; ks < 2; ++ks) {
        const f16x8 kf = *swzr(Ks, n * 16 + l15, ks * 64 + l4 * 16);
        sacc[n] = __builtin_amdgcn_mfma_f32_16x16x32_f16(qf[ks], kf, sacc[n], 0, 0, 0);
      }

    // ---- scale + bias + mask; tile row-max ----
    float p[4][4];  // [j][n]
    float tmax[4];
#pragma unroll
    for (int j = 0; j < 4; ++j) tmax[j] = -3e38f;
#pragma unroll
    for (int j = 0; j < 4; ++j)
#pragma unroll
      for (int n = 0; n < 4; ++n) {
        float s = sacc[n][j] * 0.125f + breg[j][n];
        s = mreg[j][n] ? -1e9f : s;
        p[j][n] = s;
        tmax[j] = fmaxf(tmax[j], s);
      }
#pragma unroll
    for (int j = 0; j < 4; ++j) {
      float v = tmax[j];
      v = fmaxf(v, __shfl_xor(v, 1));
      v = fmaxf(v, __shfl_xor(v, 2));
      v = fmaxf(v, __shfl_xor(v, 4));
      v = fmaxf(v, __shfl_xor(v, 8));
      tmax[j] = v;
    }

    // ---- online softmax update; write P (f16) to per-wave LDS ----
#pragma unroll
    for (int j = 0; j < 4; ++j) {
      const float mnew = fmaxf(mrow[j], tmax[j]);
      const float alpha = __builtin_exp2f((mrow[j] - mnew) * LOG2E);
      mrow[j] = mnew;
      lrow[j] *= alpha;
#pragma unroll
      for (int n = 0; n < 4; ++n) oacc[n][j] *= alpha;
      float lsum = 0.f;
      const int prow = l4 * 4 + j;
#pragma unroll
      for (int n = 0; n < 4; ++n) {
        const float e = __builtin_exp2f((p[j][n] - mnew) * LOG2E);
        lsum += e;
        const int bc = (n * 16 + l15) * 2;
        *(f16*)((char*)&Ps[w][0] + prow * 128 + (bc ^ ((prow & 7) << 4))) = (f16)e;
      }
      lsum += __shfl_xor(lsum, 1);
      lsum += __shfl_xor(lsum, 2);
      lsum += __shfl_xor(lsum, 4);
      lsum += __shfl_xor(lsum, 8);
      lrow[j] += lsum;
    }

    // ---- O += P.V ----
    f16x8 pf[2];
#pragma unroll
    for (int ks = 0; ks < 2; ++ks)
      pf[ks] = *swzr(&Ps[w][0], l15, ks * 64 + l4 * 16);
#pragma unroll
    for (int ks = 0; ks < 2; ++ks)
#pragma unroll
      for (int n = 0; n < 4; ++n) {
        const f16x8 vf = *swzr(Vs, n * 16 + l15, ks * 64 + l4 * 16);
        oacc[n] = __builtin_amdgcn_mfma_f32_16x16x32_f16(pf[ks], vf, oacc[n], 0, 0, 0);
      }
  }

  // ---- normalize and store X[b,s,h*64+dk] (f16) ----
#pragma unroll
  for (int j = 0; j < 4; ++j) {
    const float inv = 1.0f / lrow[j];
    const int qrow = q0 + l4 * 4 + j;
#pragma unroll
    for (int n = 0; n < 4; ++n) {
      const int dk = n * 16 + l15;
      X[((size_t)b * 2048 + qrow) * 1024 + h * 64 + dk] = (f16)(oacc[n][j] * inv);
    }
  }
}

// ---------------- host ------------------------------------------------------
extern "C" void kernel_launch(void* const* d_in, const int* in_sizes, int n_in,
                              void* d_out, int out_size, void* d_ws, size_t ws_size,
                              hipStream_t stream) {
  const float* query = (const float*)d_in[0];
  const float* key_ = (const float*)d_in[1];
  const float* value = (const float*)d_in[2];
  const uint8_t* mask = (const uint8_t*)d_in[3];
  const float* bias = (const float*)d_in[4];
  const float* Wq = (const float*)d_in[5];
  const float* bq = (const float*)d_in[6];
  const float* Wk = (const float*)d_in[7];
  const float* bk = (const float*)d_in[8];
  const float* Wv = (const float*)d_in[9];
  const float* bv = (const float*)d_in[10];
  const float* Wo = (const float*)d_in[11];
  const float* bo = (const float*)d_in[12];

  char* p = (char*)d_ws;
  f16* qh = (f16*)p; p += (size_t)4194304 * 2;
  f16* kh = (f16*)p; p += (size_t)4194304 * 2;
  f16* vh = (f16*)p; p += (size_t)4194304 * 2;
  f16* wqh = (f16*)p; p += (size_t)1048576 * 2;
  f16* wkh = (f16*)p; p += (size_t)1048576 * 2;
  f16* wvh = (f16*)p; p += (size_t)1048576 * 2;
  f16* woh = (f16*)p; p += (size_t)1048576 * 2;
  f16* Qp = (f16*)p; p += (size_t)4194304 * 2;
  f16* Kp = (f16*)p; p += (size_t)4194304 * 2;
  f16* Vt = (f16*)p; p += (size_t)4194304 * 2;
  f16* Xh = (f16*)p; p += (size_t)4194304 * 2;
  uint8_t* m8 = (uint8_t*)p; p += (size_t)8388608;
  int* flag = (int*)p; p += 256;
  if (ws_size < (size_t)(p - (char*)d_ws)) return;

  mask_detect<<<1, 256, 0, stream>>>(mask, flag);
  mask_canon<<<8192, 256, 0, stream>>>(mask, m8, flag);

  cvt_f32_f16<<<4096, 256, 0, stream>>>(query, qh, 1048576);
  cvt_f32_f16<<<4096, 256, 0, stream>>>(key_, kh, 1048576);
  cvt_f32_f16<<<4096, 256, 0, stream>>>(value, vh, 1048576);
  cvt_f32_f16<<<1024, 256, 0, stream>>>(Wq, wqh, 262144);
  cvt_f32_f16<<<1024, 256, 0, stream>>>(Wk, wkh, 262144);
  cvt_f32_f16<<<1024, 256, 0, stream>>>(Wv, wvh, 262144);
  cvt_f32_f16<<<1024, 256, 0, stream>>>(Wo, woh, 262144);

  gemm_bt<0><<<512, 256, 0, stream>>>(qh, wqh, bq, Qp);
  gemm_bt<0><<<512, 256, 0, stream>>>(kh, wkh, bk, Kp);
  gemm_bt<1><<<512, 256, 0, stream>>>(vh, wvh, bv, Vt);

  attn_fwd<<<1024, 256, 0, stream>>>(Qp, Kp, Vt, bias, m8, Xh);

  gemm_bt<2><<<512, 256, 0, stream>>>(Xh, woh, bo, d_out);
}